// Round 1
// baseline (581.328 us; speedup 1.0000x reference)
//
#include <hip/hip_runtime.h>
#include <hip/hip_bf16.h>
#include <stdint.h>

#define N_NODES 100000
#define N_EDGES 1600000
#define IN_DIM 128
#define HID_DIM 128
#define OUT_DIM 64

typedef __bf16 bf16x8 __attribute__((ext_vector_type(8)));
typedef float f32x4 __attribute__((ext_vector_type(4)));

__device__ __forceinline__ float bf16lo_f(uint32_t p) {
    return __uint_as_float(p << 16);
}
__device__ __forceinline__ float bf16hi_f(uint32_t p) {
    return __uint_as_float(p & 0xffff0000u);
}
__device__ __forceinline__ uint16_t f_to_bf16(float f) {
    uint32_t u = __float_as_uint(f);
    u += 0x7fffu + ((u >> 16) & 1u);   // round-to-nearest-even
    return (uint16_t)(u >> 16);
}

// ---------------- graph build ----------------

__global__ void zero_i32_k(int* __restrict__ p, int n) {
    int i = blockIdx.x * blockDim.x + threadIdx.x;
    if (i < n) p[i] = 0;
}

__global__ void hist_k(const int* __restrict__ dst, int* __restrict__ deg) {
    int e = blockIdx.x * blockDim.x + threadIdx.x;
    if (e < N_EDGES) atomicAdd(&deg[dst[e]], 1);
}

// block of 256 threads scans 1024 elements
__global__ void scan1_k(const int* __restrict__ deg, int* __restrict__ rowst,
                        int* __restrict__ partials) {
    __shared__ int sm[256];
    int tid = threadIdx.x;
    int base = blockIdx.x * 1024 + tid * 4;
    int v0 = 0, v1 = 0, v2 = 0, v3 = 0;
    if (base + 0 < N_NODES) v0 = deg[base + 0];
    if (base + 1 < N_NODES) v1 = deg[base + 1];
    if (base + 2 < N_NODES) v2 = deg[base + 2];
    if (base + 3 < N_NODES) v3 = deg[base + 3];
    int tot = v0 + v1 + v2 + v3;
    sm[tid] = tot;
    __syncthreads();
    int val = tot;
    for (int off = 1; off < 256; off <<= 1) {
        int x = (tid >= off) ? sm[tid - off] : 0;
        __syncthreads();
        val += x;
        sm[tid] = val;
        __syncthreads();
    }
    int excl = val - tot;
    if (tid == 255) partials[blockIdx.x] = val;
    if (base + 0 < N_NODES) rowst[base + 0] = excl;
    if (base + 1 < N_NODES) rowst[base + 1] = excl + v0;
    if (base + 2 < N_NODES) rowst[base + 2] = excl + v0 + v1;
    if (base + 3 < N_NODES) rowst[base + 3] = excl + v0 + v1 + v2;
}

#define NB_SCAN 98   // ceil(100000/1024)

__global__ void scan2_k(int* __restrict__ partials) {
    __shared__ int sm[128];
    int tid = threadIdx.x;
    int v = (tid < NB_SCAN) ? partials[tid] : 0;
    sm[tid] = v;
    __syncthreads();
    int val = v;
    for (int off = 1; off < 128; off <<= 1) {
        int x = (tid >= off) ? sm[tid - off] : 0;
        __syncthreads();
        val += x;
        sm[tid] = val;
        __syncthreads();
    }
    if (tid < NB_SCAN) partials[tid] = val - v;  // exclusive
}

__global__ void scan3_k(int* __restrict__ rowst, int* __restrict__ cursor,
                        const int* __restrict__ partials) {
    int i = blockIdx.x * blockDim.x + threadIdx.x;
    if (i < N_NODES) {
        int r = rowst[i] + partials[i >> 10];
        rowst[i] = r;
        cursor[i] = r;
    }
}

__global__ void scatter_k(const int* __restrict__ src, const int* __restrict__ dst,
                          int* __restrict__ cursor, int* __restrict__ csr) {
    int e = blockIdx.x * blockDim.x + threadIdx.x;
    if (e < N_EDGES) {
        int d = dst[e];
        int pos = atomicAdd(&cursor[d], 1);
        csr[pos] = src[e];
    }
}

// ---------------- dtype prep ----------------

__global__ void cast_x_k(const float* __restrict__ x, uint16_t* __restrict__ xb) {
    int i = blockIdx.x * blockDim.x + threadIdx.x;  // one float4 per thread
    if (i < N_NODES * IN_DIM / 4) {
        const float4* xv = (const float4*)x;
        float4 v = xv[i];
        union { uint16_t u[4]; uint64_t q; } o;
        o.u[0] = f_to_bf16(v.x);
        o.u[1] = f_to_bf16(v.y);
        o.u[2] = f_to_bf16(v.z);
        o.u[3] = f_to_bf16(v.w);
        ((uint64_t*)xb)[i] = o.q;
    }
}

// wT1[n][k]: n<128, k<256 (k<128 -> W1l[k][n], else W1r[k-128][n])
// wT2[n][k]: n<64,  k<256 (k<128 -> W2l[k][n], else W2r[k-128][n])
__global__ void prep_w_k(const float* __restrict__ W1l, const float* __restrict__ W1r,
                         const float* __restrict__ W2l, const float* __restrict__ W2r,
                         uint16_t* __restrict__ wT1, uint16_t* __restrict__ wT2) {
    int i = blockIdx.x * blockDim.x + threadIdx.x;
    if (i < 128 * 256) {
        int n = i >> 8, k = i & 255;
        float v = (k < 128) ? W1l[k * 128 + n] : W1r[(k - 128) * 128 + n];
        wT1[i] = f_to_bf16(v);
    } else {
        int j = i - 128 * 256;
        if (j < 64 * 256) {
            int n = j >> 8, k = j & 255;
            float v = (k < 128) ? W2l[k * 64 + n] : W2r[(k - 128) * 64 + n];
            wT2[j] = f_to_bf16(v);
        }
    }
}

// ---------------- mean aggregation (one wave per node) ----------------
// in2/out2: rows of 128 bf16 viewed as 64 uint32 (bf16x2), lane handles 2 cols

__global__ void aggregate_k(const int* __restrict__ csr, const int* __restrict__ rowst,
                            const int* __restrict__ deg,
                            const uint32_t* __restrict__ in2, uint32_t* __restrict__ out2) {
    int gw = (blockIdx.x * blockDim.x + threadIdx.x) >> 6;
    int lane = threadIdx.x & 63;
    if (gw >= N_NODES) return;
    int start = rowst[gw];
    int d = deg[gw];
    float a0 = 0.f, a1 = 0.f;
    int j = 0;
    for (; j + 1 < d; j += 2) {
        int s0 = csr[start + j];
        int s1 = csr[start + j + 1];
        uint32_t p0 = in2[s0 * 64 + lane];
        uint32_t p1 = in2[s1 * 64 + lane];
        a0 += bf16lo_f(p0); a1 += bf16hi_f(p0);
        a0 += bf16lo_f(p1); a1 += bf16hi_f(p1);
    }
    if (j < d) {
        int s0 = csr[start + j];
        uint32_t p0 = in2[s0 * 64 + lane];
        a0 += bf16lo_f(p0); a1 += bf16hi_f(p0);
    }
    float inv = 1.0f / (float)(d > 0 ? d : 1);
    a0 *= inv; a1 *= inv;
    uint32_t o = (uint32_t)f_to_bf16(a0) | ((uint32_t)f_to_bf16(a1) << 16);
    out2[gw * 64 + lane] = o;
}

// ---------------- GEMMs: [aggr | root] (M x 256) @ wT (N x 256)^T ----------------
// mfma_f32_16x16x32_bf16: A lane m=lane&15, k=quad*8+j ; B lane n=lane&15, k=quad*8+j
// C/D lane: col=lane&15, row=quad*4+reg   [m89-verified]

__global__ __launch_bounds__(256) void gemm1_k(const uint16_t* __restrict__ ab,
                                               const uint16_t* __restrict__ xb,
                                               const uint16_t* __restrict__ wT1,
                                               const float* __restrict__ b1,
                                               uint16_t* __restrict__ hb) {
    int wave = (blockIdx.x * 256 + threadIdx.x) >> 6;
    int lane = threadIdx.x & 63;
    int m0 = wave * 16;
    if (m0 >= N_NODES) return;
    int mr = lane & 15, quad = lane >> 4;

    const uint16_t* A1 = ab + (size_t)(m0 + mr) * 128 + quad * 8;
    const uint16_t* A2 = xb + (size_t)(m0 + mr) * 128 + quad * 8;

    f32x4 acc[8];
#pragma unroll
    for (int nt = 0; nt < 8; nt++) acc[nt] = (f32x4){0.f, 0.f, 0.f, 0.f};

#pragma unroll
    for (int kt = 0; kt < 8; kt++) {
        const uint16_t* ap = (kt < 4) ? (A1 + kt * 32) : (A2 + (kt - 4) * 32);
        bf16x8 a = *reinterpret_cast<const bf16x8*>(ap);
#pragma unroll
        for (int nt = 0; nt < 8; nt++) {
            const uint16_t* bp = wT1 + (size_t)(nt * 16 + mr) * 256 + kt * 32 + quad * 8;
            bf16x8 b = *reinterpret_cast<const bf16x8*>(bp);
            acc[nt] = __builtin_amdgcn_mfma_f32_16x16x32_bf16(a, b, acc[nt], 0, 0, 0);
        }
    }

#pragma unroll
    for (int nt = 0; nt < 8; nt++) {
        int col = nt * 16 + mr;
        float bias = b1[col];
#pragma unroll
        for (int r = 0; r < 4; r++) {
            int row = m0 + quad * 4 + r;
            float v = acc[nt][r] + bias;
            v = v > 0.f ? v : 0.f;
            hb[(size_t)row * 128 + col] = f_to_bf16(v);
        }
    }
}

__global__ __launch_bounds__(256) void gemm2_k(const uint16_t* __restrict__ ab2,
                                               const uint16_t* __restrict__ hb,
                                               const uint16_t* __restrict__ wT2,
                                               const float* __restrict__ b2,
                                               float* __restrict__ out) {
    int wave = (blockIdx.x * 256 + threadIdx.x) >> 6;
    int lane = threadIdx.x & 63;
    int m0 = wave * 16;
    if (m0 >= N_NODES) return;
    int mr = lane & 15, quad = lane >> 4;

    const uint16_t* A1 = ab2 + (size_t)(m0 + mr) * 128 + quad * 8;
    const uint16_t* A2 = hb + (size_t)(m0 + mr) * 128 + quad * 8;

    f32x4 acc[4];
#pragma unroll
    for (int nt = 0; nt < 4; nt++) acc[nt] = (f32x4){0.f, 0.f, 0.f, 0.f};

#pragma unroll
    for (int kt = 0; kt < 8; kt++) {
        const uint16_t* ap = (kt < 4) ? (A1 + kt * 32) : (A2 + (kt - 4) * 32);
        bf16x8 a = *reinterpret_cast<const bf16x8*>(ap);
#pragma unroll
        for (int nt = 0; nt < 4; nt++) {
            const uint16_t* bp = wT2 + (size_t)(nt * 16 + mr) * 256 + kt * 32 + quad * 8;
            bf16x8 b = *reinterpret_cast<const bf16x8*>(bp);
            acc[nt] = __builtin_amdgcn_mfma_f32_16x16x32_bf16(a, b, acc[nt], 0, 0, 0);
        }
    }

#pragma unroll
    for (int nt = 0; nt < 4; nt++) {
        int col = nt * 16 + mr;
        float bias = b2[col];
#pragma unroll
        for (int r = 0; r < 4; r++) {
            int row = m0 + quad * 4 + r;
            out[(size_t)row * 64 + col] = acc[nt][r] + bias;
        }
    }
}

// ---------------- launch ----------------

extern "C" void kernel_launch(void* const* d_in, const int* in_sizes, int n_in,
                              void* d_out, int out_size, void* d_ws, size_t ws_size,
                              hipStream_t stream) {
    const float* x   = (const float*)d_in[0];
    const int*  ei   = (const int*)d_in[1];
    const float* W1l = (const float*)d_in[2];
    const float* b1  = (const float*)d_in[3];
    const float* W1r = (const float*)d_in[4];
    const float* W2l = (const float*)d_in[5];
    const float* b2  = (const float*)d_in[6];
    const float* W2r = (const float*)d_in[7];
    float* out = (float*)d_out;

    const int* srcv = ei;            // edge_index[0]
    const int* dstv = ei + N_EDGES;  // edge_index[1]

    char* ws = (char*)d_ws;
    int*      deg      = (int*)(ws + 0);
    int*      rowst    = (int*)(ws + 401408);
    int*      cursor   = (int*)(ws + 802816);
    int*      partials = (int*)(ws + 1204224);
    int*      csr      = (int*)(ws + 1205248);
    uint16_t* wT1      = (uint16_t*)(ws + 7605248);
    uint16_t* wT2      = (uint16_t*)(ws + 7670784);
    uint16_t* xb       = (uint16_t*)(ws + 7703552);
    uint16_t* ab       = (uint16_t*)(ws + 33303552);
    uint16_t* hb       = (uint16_t*)(ws + 58903552);
    // total ws use: ~84.5 MB

    zero_i32_k<<<391, 256, 0, stream>>>(deg, N_NODES);
    hist_k<<<6250, 256, 0, stream>>>(dstv, deg);
    scan1_k<<<NB_SCAN, 256, 0, stream>>>(deg, rowst, partials);
    scan2_k<<<1, 128, 0, stream>>>(partials);
    scan3_k<<<391, 256, 0, stream>>>(rowst, cursor, partials);
    scatter_k<<<6250, 256, 0, stream>>>(srcv, dstv, cursor, csr);

    cast_x_k<<<12500, 256, 0, stream>>>(x, xb);
    prep_w_k<<<192, 256, 0, stream>>>(W1l, W1r, W2l, W2r, wT1, wT2);

    // layer 1: aggr(x) -> ab ; h = relu([ab|x] @ wT1^T + b1) -> hb
    aggregate_k<<<25000, 256, 0, stream>>>(csr, rowst, deg, (const uint32_t*)xb, (uint32_t*)ab);
    gemm1_k<<<1563, 256, 0, stream>>>(ab, xb, wT1, b1, hb);

    // layer 2: aggr(h) -> xb (reuse) ; out = [xb|hb] @ wT2^T + b2
    aggregate_k<<<25000, 256, 0, stream>>>(csr, rowst, deg, (const uint32_t*)hb, (uint32_t*)xb);
    gemm2_k<<<1563, 256, 0, stream>>>((const uint16_t*)xb, hb, wT2, b2, out);
}